// Round 3
// baseline (143.380 us; speedup 1.0000x reference)
//
#include <hip/hip_runtime.h>

typedef unsigned short u16;
typedef unsigned int u32;
typedef __attribute__((ext_vector_type(8))) __bf16 bf16x8;
typedef __attribute__((ext_vector_type(4))) float f32x4;
typedef __attribute__((ext_vector_type(4))) u16 u16x4;

#define MFMA16(a, b, c) __builtin_amdgcn_mfma_f32_16x16x32_bf16((a), (b), (c), 0, 0, 0)

static __device__ __forceinline__ u16 f2b(float f) {
  union { float f; u32 u; } v; v.f = f;
  u32 u = v.u;
  return (u16)((u + 0x7FFFu + ((u >> 16) & 1u)) >> 16);
}

static __device__ __forceinline__ float b2f(u16 s) {
  union { u32 u; float f; } c; c.u = (u32)s << 16; return c.f;
}

// packed f32x2 -> bf16x2 (RNE), low half = a
static __device__ __forceinline__ u32 pack2(float a, float b) {
  u32 r;
  asm("v_cvt_pk_bf16_f32 %0, %1, %2" : "=v"(r) : "v"(a), "v"(b));
  return r;
}

static __device__ __forceinline__ float exp2fast(float x) {
#if defined(__has_builtin) && __has_builtin(__builtin_amdgcn_exp2f)
  return __builtin_amdgcn_exp2f(x);
#else
  return __expf(x * 0.6931471805599453f);
#endif
}

static __device__ __forceinline__ void gload16(const u16* gp, u16* lp) {
  __builtin_amdgcn_global_load_lds((__attribute__((address_space(1))) void*)(u16*)gp,
                                   (__attribute__((address_space(3))) void*)lp, 16, 0, 0);
}

// ---------------- merged prep kernel ----------------
// blocks [0,3072): Wqkv [1024][3072] -> WB [3072][1024] bf16 transpose
// blocks [3072,4096): Wout [1024][1024] -> WoT transpose
// blocks [4096,4608): W1p/W2p -> WB rows 3072..3199
// blocks [4608,6656): x f32 -> xb bf16
__global__ __launch_bounds__(256) void k_prep(const float* __restrict__ Wqkv, const float* __restrict__ Wout,
                                              const float* __restrict__ W1p, const float* __restrict__ W2p,
                                              const float* __restrict__ x,
                                              u16* __restrict__ WB, u16* __restrict__ WoT,
                                              u16* __restrict__ xb) {
  const int b = blockIdx.x;
  const int t = threadIdx.x;
  if (b < 4096) {
    __shared__ float tile[32][33];
    const float* src; u16* dst; int N, n0, k0;
    if (b < 3072) { src = Wqkv; dst = WB;  N = 3072; n0 = (b % 96) * 32; k0 = (b / 96) * 32; }
    else { const int bb = b - 3072; src = Wout; dst = WoT; N = 1024; n0 = (bb & 31) * 32; k0 = (bb >> 5) * 32; }
    const int r = t >> 3, c4 = (t & 7) << 2;
    const float4 in4 = *(const float4*)(src + (size_t)(k0 + r) * N + n0 + c4);
    tile[r][c4 + 0] = in4.x; tile[r][c4 + 1] = in4.y;
    tile[r][c4 + 2] = in4.z; tile[r][c4 + 3] = in4.w;
    __syncthreads();
    u16x4 o;
    o.x = f2b(tile[c4 + 0][r]); o.y = f2b(tile[c4 + 1][r]);
    o.z = f2b(tile[c4 + 2][r]); o.w = f2b(tile[c4 + 3][r]);
    *(u16x4*)(dst + (size_t)(n0 + r) * 1024 + k0 + c4) = o;
  } else if (b < 4608) {
    const int idx = (b - 4096) * 256 + t;  // 131072
    const int j = idx >> 10, k = idx & 1023;
    const float v = (j < 64) ? W1p[(size_t)k * 64 + j] : W2p[(size_t)k * 64 + (j - 64)];
    WB[(size_t)3072 * 1024 + idx] = f2b(v);
  } else {
    const size_t idx = ((size_t)(b - 4608) * 256 + t) << 2;
    const float4 v = *(const float4*)(x + idx);
    u16x4 o; o.x = f2b(v.x); o.y = f2b(v.y); o.z = f2b(v.z); o.w = f2b(v.w);
    *(u16x4*)(xb + idx) = o;
  }
}

// ---------------- 128x64 bf16 MFMA GEMM core (BK=64, global_load_lds, XOR swizzle) ----------------
static __device__ __forceinline__ void gemm_core_128x64(const u16* __restrict__ A, const u16* __restrict__ B,
                                                        int brow, int bcol, int K,
                                                        u16* ldsA, u16* ldsB, f32x4 acc[4][2]) {
  const int tid = threadIdx.x;
  const int wave = tid >> 6, lane = tid & 63;
  const int wr = wave >> 1, wc = wave & 1;
  const int g = lane >> 4, l15 = lane & 15;

  for (int k0 = 0; k0 < K; k0 += 64) {
#pragma unroll
    for (int li = 0; li < 4; ++li) {
      const int f = li * 256 + wave * 64 + lane;
      const int row = f >> 3;
      const int slot = f & 7;
      const int gcol = ((slot ^ (row & 7)) << 3);
      gload16(A + (size_t)(brow + row) * K + k0 + gcol, ldsA + (size_t)(li * 256 + wave * 64) * 8);
    }
#pragma unroll
    for (int li = 0; li < 2; ++li) {
      const int f = li * 256 + wave * 64 + lane;
      const int row = f >> 3;
      const int slot = f & 7;
      const int gcol = ((slot ^ (row & 7)) << 3);
      gload16(B + (size_t)(bcol + row) * K + k0 + gcol, ldsB + (size_t)(li * 256 + wave * 64) * 8);
    }
    __syncthreads();
    bf16x8 af[4][2], bfr[2][2];
#pragma unroll
    for (int kk = 0; kk < 2; ++kk) {
#pragma unroll
      for (int m = 0; m < 4; ++m) {
        const int rowA = wr * 64 + m * 16 + l15;
        const int chA = (kk * 4 + g) ^ (rowA & 7);
        af[m][kk] = *(const bf16x8*)(ldsA + (size_t)rowA * 64 + chA * 8);
      }
#pragma unroll
      for (int n = 0; n < 2; ++n) {
        const int rowB = wc * 32 + n * 16 + l15;
        const int chB = (kk * 4 + g) ^ (rowB & 7);
        bfr[n][kk] = *(const bf16x8*)(ldsB + (size_t)rowB * 64 + chB * 8);
      }
    }
#pragma unroll
    for (int m = 0; m < 4; ++m)
#pragma unroll
      for (int n = 0; n < 2; ++n)
#pragma unroll
        for (int kk = 0; kk < 2; ++kk)
          acc[m][n] = MFMA16(af[m][kk], bfr[n][kk], acc[m][n]);
    __syncthreads();
  }
}

// ---------------- GEMM1: x @ [Wqkv|W1p|W2p]  (M=2048, N=3200, K=1024) ----------------
// Q prescale = 0.125 * log2(e) so attention can use exp2 directly.
__global__ __launch_bounds__(256) void k_gemm_qkvp(const u16* __restrict__ xb, const u16* __restrict__ WB,
                                                   const float* __restrict__ bqkv,
                                                   u16* __restrict__ Qext, u16* __restrict__ Kext,
                                                   u16* __restrict__ Vt, float* __restrict__ P12) {
  __shared__ __align__(16) u16 ldsA[128 * 64];
  __shared__ __align__(16) u16 ldsB[64 * 64];
  const int bid = blockIdx.x;                      // 800 blocks
  const int bn = bid % 50, bm = bid / 50;
  f32x4 acc[4][2];
#pragma unroll
  for (int m = 0; m < 4; ++m)
#pragma unroll
    for (int n = 0; n < 2; ++n) acc[m][n] = (f32x4){0.f, 0.f, 0.f, 0.f};
  gemm_core_128x64(xb, WB, bm * 128, bn * 64, 1024, ldsA, ldsB, acc);

  const int tid = threadIdx.x;
  const int wave = tid >> 6, lane = tid & 63;
  const int wr = wave >> 1, wc = wave & 1;
  const int g = lane >> 4, l15 = lane & 15;
  const int tbase = bm * 128 + wr * 64 + g * 4;
  const int cbase = bn * 64 + wc * 32 + l15;
#pragma unroll
  for (int m = 0; m < 4; ++m) {
#pragma unroll
    for (int n = 0; n < 2; ++n) {
      const int c = cbase + n * 16;
#pragma unroll
      for (int r = 0; r < 4; ++r) {
        const int t = tbase + m * 16 + r;
        float v = acc[m][n][r];
        if (c < 3072) {
          v += bqkv[c];
          const int sub = c >> 10;
          const int rem = c & 1023;
          const int hh = rem >> 6, d = rem & 63;
          if (sub == 0)      Qext[((size_t)hh * 2048 + t) * 96 + d] = f2b(v * 0.18033688f);
          else if (sub == 1) Kext[((size_t)hh * 2048 + t) * 96 + d] = f2b(v);
          else               Vt[((size_t)hh * 64 + d) * 2048 + t] = f2b(v);
        } else {
          P12[(size_t)t * 128 + (c - 3072)] = v;
        }
      }
    }
  }
}

// ---------------- Plucker lines -> Qext/Kext cols 64..95 ----------------
__global__ __launch_bounds__(256) void k_lines(const float* __restrict__ P12, const float* __restrict__ pscale,
                                               u16* __restrict__ Qext, u16* __restrict__ Kext) {
  const int idx = blockIdx.x * 256 + threadIdx.x;  // 32768 = 2048*16
  const int t = idx >> 4, h = idx & 15;
  const float* p = P12 + (size_t)t * 128;
  const float a0 = p[h * 4 + 0], a1 = p[h * 4 + 1], a2 = p[h * 4 + 2], a3 = p[h * 4 + 3];
  const float b0 = p[64 + h * 4 + 0], b1 = p[64 + h * 4 + 1], b2 = p[64 + h * 4 + 2], b3 = p[64 + h * 4 + 3];
  float L0 = a0 * b1 - a1 * b0;
  float L1 = a0 * b2 - a2 * b0;
  float L2 = a0 * b3 - a3 * b0;
  float L3 = a1 * b2 - a2 * b1;
  float L4 = a1 * b3 - a3 * b1;
  float L5 = a2 * b3 - a3 * b2;
  const float nrm = sqrtf(L0 * L0 + L1 * L1 + L2 * L2 + L3 * L3 + L4 * L4 + L5 * L5);
  const float inv = 1.0f / fmaxf(nrm, 1e-12f);
  L0 *= inv; L1 *= inv; L2 *= inv; L3 *= inv; L4 *= inv; L5 *= inv;
  const float s = pscale[h] * 1.44269504f;  // fold log2(e) into q-side bias
  u16* q = Qext + ((size_t)h * 2048 + t) * 96 + 64;
  u16* k = Kext + ((size_t)h * 2048 + t) * 96 + 64;
  q[0] = f2b(L0 * s); q[1] = f2b(L1 * s); q[2] = f2b(L2 * s);
  q[3] = f2b(L3 * s); q[4] = f2b(L4 * s); q[5] = f2b(L5 * s);
  // Jlines = J6 @ L : [L5, -L4, L3, L2, -L1, L0]
  k[0] = f2b(L5); k[1] = f2b(-L4); k[2] = f2b(L3);
  k[3] = f2b(L2); k[4] = f2b(-L1); k[5] = f2b(L0);
#pragma unroll
  for (int c = 6; c < 32; ++c) { q[c] = 0; k[c] = 0; }
}

// ---------------- fused causal attention, no-max exp2 softmax, split-KV ----------------
// S^T = mfma(K,Q): lane holds col q=lane&15, rows k=(lane>>4)*4+r. No running max (logits bounded);
// l is a deferred per-lane partial. Partials (unnormalized O^T bf16, l f32) written per split;
// k_comb sums splits and normalizes. grid = 512*nsplit.
__global__ __launch_bounds__(256) void k_attn(const u16* __restrict__ Qext, const u16* __restrict__ Kext,
                                              const u16* __restrict__ Vt,
                                              u16* __restrict__ Op0, u16* __restrict__ Op1,
                                              float* __restrict__ lp0, float* __restrict__ lp1,
                                              int nsplit) {
  const int idx = blockIdx.x;
  const int split = idx >> 9;
  const int sub = idx & 511;
  const int half = sub >> 8;
  const int qt_raw = (sub & 255) >> 4;
  const int qt = half ? (31 - qt_raw) : qt_raw;   // pair long+short tiles per CU
  const int h = idx & 15;                         // consecutive blocks -> head ~ XCD affinity
  const int wave = threadIdx.x >> 6, lane = threadIdx.x & 63;
  const int g = lane >> 4, l15 = lane & 15;
  const int q0 = qt * 64 + wave * 16;
  const int q_glob = q0 + l15;
  const u16* Qh = Qext + (size_t)h * 2048 * 96;
  const u16* Kh = Kext + (size_t)h * 2048 * 96;
  const u16* Vh = Vt + (size_t)h * 64 * 2048;

  bf16x8 aq[3];  // Q as B-fragment: col q=l15, contraction c = ks*32 + g*8 + e
#pragma unroll
  for (int ks = 0; ks < 3; ++ks)
    aq[ks] = *(const bf16x8*)(Qh + (size_t)q_glob * 96 + ks * 32 + g * 8);

  f32x4 accO[4];
#pragma unroll
  for (int n = 0; n < 4; ++n) accO[n] = (f32x4){0.f, 0.f, 0.f, 0.f};
  float lrun = 0.f;

  const int N = (q0 >> 5) + 1;   // total 32-wide KV steps for this wave
  int sBeg = 0, sEnd = N;
  if (nsplit == 2) { const int mid = N >> 1; if (split) sBeg = mid; else sEnd = mid; }

  const u16* Kbase = Kh + (size_t)l15 * 96 + g * 8;
  bf16x8 kA0[3], kA1[3], kB0[3], kB1[3];

#define ATTN_STEP(KC0, KC1, KN0, KN1)                                             \
  {                                                                               \
    const int jb = jt * 32;                                                       \
    const bf16x8 av0 = *(const bf16x8*)(Vh + (size_t)l15 * 2048 + jb + g * 8);    \
    const bf16x8 av1 = *(const bf16x8*)(Vh + (size_t)(16 + l15) * 2048 + jb + g * 8); \
    const bf16x8 av2 = *(const bf16x8*)(Vh + (size_t)(32 + l15) * 2048 + jb + g * 8); \
    const bf16x8 av3 = *(const bf16x8*)(Vh + (size_t)(48 + l15) * 2048 + jb + g * 8); \
    const int jbn = (jt + 1 < sEnd) ? jb + 32 : jb;                               \
    const u16* kp = Kbase + (size_t)jbn * 96;                                     \
    _Pragma("unroll")                                                             \
    for (int ks = 0; ks < 3; ++ks) {                                              \
      KN0[ks] = *(const bf16x8*)(kp + ks * 32);                                   \
      KN1[ks] = *(const bf16x8*)(kp + 16 * 96 + ks * 32);                         \
    }                                                                             \
    f32x4 S0 = (f32x4){0.f, 0.f, 0.f, 0.f}, S1 = (f32x4){0.f, 0.f, 0.f, 0.f};     \
    __builtin_amdgcn_s_setprio(1);                                                \
    _Pragma("unroll")                                                             \
    for (int ks = 0; ks < 3; ++ks) {                                              \
      S0 = MFMA16(KC0[ks], aq[ks], S0);                                           \
      S1 = MFMA16(KC1[ks], aq[ks], S1);                                           \
    }                                                                             \
    __builtin_amdgcn_s_setprio(0);                                                \
    if (jb + 31 > q0) {                                                           \
      _Pragma("unroll")                                                           \
      for (int r = 0; r < 4; ++r) {                                               \
        if (jb + g * 4 + r > q_glob) S0[r] = -1e30f;                              \
        if (jb + 16 + g * 4 + r > q_glob) S1[r] = -1e30f;                         \
      }                                                                           \
    }                                                                             \
    _Pragma("unroll")                                                             \
    for (int r = 0; r < 4; ++r) {                                                 \
      S0[r] = exp2fast(S0[r]);                                                    \
      S1[r] = exp2fast(S1[r]);                                                    \
    }                                                                             \
    lrun += ((S0[0] + S0[1]) + (S0[2] + S0[3])) + ((S1[0] + S1[1]) + (S1[2] + S1[3])); \
    const u32 w0 = pack2(S0[0], S0[1]);                                           \
    const u32 w1 = pack2(S0[2], S0[3]);                                           \
    const u32 w2 = pack2(S1[0], S1[1]);                                           \
    const u32 w3 = pack2(S1[2], S1[3]);                                           \
    const int src0 = ((g & 1) << 5) + l15;                                        \
    const int src1 = src0 + 16;                                                   \
    const u32 a0 = (u32)__shfl((int)w0, src0);                                    \
    const u32 a1 = (u32)__shfl((int)w2, src0);                                    \
    const u32 b0 = (u32)__shfl((int)w1, src0);                                    \
    const u32 b1 = (u32)__shfl((int)w3, src0);                                    \
    const u32 c0 = (u32)__shfl((int)w0, src1);                                    \
    const u32 c1 = (u32)__shfl((int)w2, src1);                                    \
    const u32 d0 = (u32)__shfl((int)w1, src1);                                    \
    const u32 d1 = (u32)__shfl((int)w3, src1);                                    \
    union { u32 u[4]; bf16x8 bv; } pb;                                            \
    pb.u[0] = (g & 2) ? a1 : a0;                                                  \
    pb.u[1] = (g & 2) ? b1 : b0;                                                  \
    pb.u[2] = (g & 2) ? c1 : c0;                                                  \
    pb.u[3] = (g & 2) ? d1 : d0;                                                  \
    __builtin_amdgcn_s_setprio(1);                                                \
    accO[0] = MFMA16(av0, pb.bv, accO[0]);                                        \
    accO[1] = MFMA16(av1, pb.bv, accO[1]);                                        \
    accO[2] = MFMA16(av2, pb.bv, accO[2]);                                        \
    accO[3] = MFMA16(av3, pb.bv, accO[3]);                                        \
    __builtin_amdgcn_s_setprio(0);                                                \
  }

  int jt = sBeg;
  if (jt < sEnd) {
    const u16* kp0 = Kbase + (size_t)jt * 32 * 96;
#pragma unroll
    for (int ks = 0; ks < 3; ++ks) {
      kA0[ks] = *(const bf16x8*)(kp0 + ks * 32);
      kA1[ks] = *(const bf16x8*)(kp0 + 16 * 96 + ks * 32);
    }
    for (;;) {
      ATTN_STEP(kA0, kA1, kB0, kB1);
      if (++jt >= sEnd) break;
      ATTN_STEP(kB0, kB1, kA0, kA1);
      if (++jt >= sEnd) break;
    }
  }
#undef ATTN_STEP

  // store unnormalized partials (zeros if this split had no steps)
  u16* Op = split ? Op1 : Op0;
  float* lp = split ? lp1 : lp0;
  const size_t sb = ((size_t)h * 2048 + q_glob) * 64 + g * 4;
#pragma unroll
  for (int n = 0; n < 4; ++n) {
    uint2 w;
    w.x = pack2(accO[n][0], accO[n][1]);
    w.y = pack2(accO[n][2], accO[n][3]);
    *(uint2*)(Op + sb + n * 16) = w;
  }
  lrun += __shfl_xor(lrun, 16);
  lrun += __shfl_xor(lrun, 32);
  if (lane < 16) lp[(size_t)h * 2048 + q_glob] = lrun;
}

// ---------------- combine: AO[q][h*64+d] = (O0+O1)/(l0+l1) ----------------
__global__ __launch_bounds__(256) void k_comb(const u16* __restrict__ Op0, const u16* __restrict__ Op1,
                                              const float* __restrict__ lp0, const float* __restrict__ lp1,
                                              u16* __restrict__ AO, int nsplit) {
  const int idx = blockIdx.x * 256 + threadIdx.x;  // 262144
  const int d8 = idx & 7;
  const int hq = idx >> 3;          // h*2048 + q
  const int q = hq & 2047, h = hq >> 11;
  float l = lp0[hq];
  union { uint4 v; u16 s[8]; } a;
  a.v = *(const uint4*)(Op0 + (size_t)hq * 64 + d8 * 8);
  float o[8];
#pragma unroll
  for (int i = 0; i < 8; ++i) o[i] = b2f(a.s[i]);
  if (nsplit == 2) {
    l += lp1[hq];
    union { uint4 v; u16 s[8]; } bb;
    bb.v = *(const uint4*)(Op1 + (size_t)hq * 64 + d8 * 8);
#pragma unroll
    for (int i = 0; i < 8; ++i) o[i] += b2f(bb.s[i]);
  }
  const float inv = 1.0f / l;
  uint4 w;
  w.x = pack2(o[0] * inv, o[1] * inv);
  w.y = pack2(o[2] * inv, o[3] * inv);
  w.z = pack2(o[4] * inv, o[5] * inv);
  w.w = pack2(o[6] * inv, o[7] * inv);
  *(uint4*)(AO + (size_t)q * 1024 + h * 64 + d8 * 8) = w;
}

// ---------------- GEMM out: AO @ WoutT + bout  (M=2048, N=1024, K=1024) ----------------
__global__ __launch_bounds__(256) void k_gemm_out(const u16* __restrict__ AO, const u16* __restrict__ WoT,
                                                  const float* __restrict__ bout, float* __restrict__ out) {
  __shared__ __align__(16) u16 ldsA[128 * 64];
  __shared__ __align__(16) u16 ldsB[64 * 64];
  const int bid = blockIdx.x;                     // 256 blocks
  const int bn = bid & 15, bm = bid >> 4;
  f32x4 acc[4][2];
#pragma unroll
  for (int m = 0; m < 4; ++m)
#pragma unroll
    for (int n = 0; n < 2; ++n) acc[m][n] = (f32x4){0.f, 0.f, 0.f, 0.f};
  gemm_core_128x64(AO, WoT, bm * 128, bn * 64, 1024, ldsA, ldsB, acc);

  const int tid = threadIdx.x;
  const int wave = tid >> 6, lane = tid & 63;
  const int wr = wave >> 1, wc = wave & 1;
  const int g = lane >> 4, l15 = lane & 15;
  const int tbase = bm * 128 + wr * 64 + g * 4;
  const int cbase = bn * 64 + wc * 32 + l15;
#pragma unroll
  for (int m = 0; m < 4; ++m)
#pragma unroll
    for (int n = 0; n < 2; ++n) {
      const int c = cbase + n * 16;
      const float bb = bout[c];
#pragma unroll
      for (int r = 0; r < 4; ++r) {
        const int t = tbase + m * 16 + r;
        out[(size_t)t * 1024 + c] = acc[m][n][r] + bb;
      }
    }
}

// ---------------- launch ----------------
extern "C" void kernel_launch(void* const* d_in, const int* in_sizes, int n_in,
                              void* d_out, int out_size, void* d_ws, size_t ws_size,
                              hipStream_t stream) {
  const float* x      = (const float*)d_in[0];
  const float* Wqkv   = (const float*)d_in[1];
  const float* bqkv   = (const float*)d_in[2];
  const float* W1p    = (const float*)d_in[3];
  const float* W2p    = (const float*)d_in[4];
  const float* pscale = (const float*)d_in[5];
  const float* Wout   = (const float*)d_in[6];
  const float* bout   = (const float*)d_in[7];
  float* out = (float*)d_out;

  char* ws = (char*)d_ws;
  u16*   WB    = (u16*)(ws + 0);          // [3200][1024] bf16
  u16*   WoT   = (u16*)(ws + 6553600);    // [1024][1024] bf16
  u16*   xb    = (u16*)(ws + 8650752);    // [2048][1024] bf16 (reused as Opart0 after gemm)
  u16*   Qext  = (u16*)(ws + 12845056);   // [16][2048][96] bf16 (q*0.1803 | s*log2e*L | 0)
  u16*   Kext  = (u16*)(ws + 19136512);   // [16][2048][96] bf16 (k | J·L | 0)
  u16*   Vt    = (u16*)(ws + 25427968);   // [16][64][2048] bf16
  float* P12   = (float*)(ws + 29622272); // [2048][128] f32 (reused as lpart0 after k_lines)
  u16*   AO    = (u16*)(ws + 30670848);   // [2048][1024] bf16

  u16*   Op0   = xb;                      // [16][2048][64] bf16 unnormalized O, split 0
  float* lp0   = P12;                     // [16][2048] f32
  u16*   Op1   = (u16*)(ws + 34865152);   // split 1 (only if ws allows)
  float* lp1   = (float*)(ws + 39059456);
  const int nsplit = (ws_size >= 39190528ull) ? 2 : 1;
  if (nsplit == 1) { Op1 = Op0; lp1 = lp0; }

  k_prep<<<6656, 256, 0, stream>>>(Wqkv, Wout, W1p, W2p, x, WB, WoT, xb);
  k_gemm_qkvp<<<800, 256, 0, stream>>>(xb, WB, bqkv, Qext, Kext, Vt, P12);
  k_lines<<<128, 256, 0, stream>>>(P12, pscale, Qext, Kext);
  k_attn<<<512 * nsplit, 256, 0, stream>>>(Qext, Kext, Vt, Op0, Op1, lp0, lp1, nsplit);
  k_comb<<<1024, 256, 0, stream>>>(Op0, Op1, lp0, lp1, AO, nsplit);
  k_gemm_out<<<256, 256, 0, stream>>>(AO, WoT, bout, out);
}

// Round 4
// 119.703 us; speedup vs baseline: 1.1978x; 1.1978x over previous
//
#include <hip/hip_runtime.h>

typedef unsigned short u16;
typedef unsigned int u32;
typedef __attribute__((ext_vector_type(8))) __bf16 bf16x8;
typedef __attribute__((ext_vector_type(4))) float f32x4;
typedef __attribute__((ext_vector_type(4))) u16 u16x4;

#define MFMA16(a, b, c) __builtin_amdgcn_mfma_f32_16x16x32_bf16((a), (b), (c), 0, 0, 0)

static __device__ __forceinline__ u16 f2b(float f) {
  union { float f; u32 u; } v; v.f = f;
  u32 u = v.u;
  return (u16)((u + 0x7FFFu + ((u >> 16) & 1u)) >> 16);
}

// packed f32x2 -> bf16x2 (RNE), low half = a
static __device__ __forceinline__ u32 pack2(float a, float b) {
  u32 r;
  asm("v_cvt_pk_bf16_f32 %0, %1, %2" : "=v"(r) : "v"(a), "v"(b));
  return r;
}

static __device__ __forceinline__ float exp2fast(float x) {
#if defined(__has_builtin) && __has_builtin(__builtin_amdgcn_exp2f)
  return __builtin_amdgcn_exp2f(x);
#else
  return __expf(x * 0.6931471805599453f);
#endif
}

static __device__ __forceinline__ void gload16(const u16* gp, u16* lp) {
  __builtin_amdgcn_global_load_lds((__attribute__((address_space(1))) void*)(u16*)gp,
                                   (__attribute__((address_space(3))) void*)lp, 16, 0, 0);
}

// ---------------- merged prep kernel ----------------
// blocks [0,3072): Wqkv [1024][3072] -> WB [3072][1024] bf16 transpose
// blocks [3072,4096): Wout [1024][1024] -> WoT transpose
// blocks [4096,4608): W1p/W2p -> WB rows 3072..3199
// blocks [4608,6656): x f32 -> xb bf16
__global__ __launch_bounds__(256) void k_prep(const float* __restrict__ Wqkv, const float* __restrict__ Wout,
                                              const float* __restrict__ W1p, const float* __restrict__ W2p,
                                              const float* __restrict__ x,
                                              u16* __restrict__ WB, u16* __restrict__ WoT,
                                              u16* __restrict__ xb) {
  const int b = blockIdx.x;
  const int t = threadIdx.x;
  if (b < 4096) {
    __shared__ float tile[32][33];
    const float* src; u16* dst; int N, n0, k0;
    if (b < 3072) { src = Wqkv; dst = WB;  N = 3072; n0 = (b % 96) * 32; k0 = (b / 96) * 32; }
    else { const int bb = b - 3072; src = Wout; dst = WoT; N = 1024; n0 = (bb & 31) * 32; k0 = (bb >> 5) * 32; }
    const int r = t >> 3, c4 = (t & 7) << 2;
    const float4 in4 = *(const float4*)(src + (size_t)(k0 + r) * N + n0 + c4);
    tile[r][c4 + 0] = in4.x; tile[r][c4 + 1] = in4.y;
    tile[r][c4 + 2] = in4.z; tile[r][c4 + 3] = in4.w;
    __syncthreads();
    u16x4 o;
    o.x = f2b(tile[c4 + 0][r]); o.y = f2b(tile[c4 + 1][r]);
    o.z = f2b(tile[c4 + 2][r]); o.w = f2b(tile[c4 + 3][r]);
    *(u16x4*)(dst + (size_t)(n0 + r) * 1024 + k0 + c4) = o;
  } else if (b < 4608) {
    const int idx = (b - 4096) * 256 + t;  // 131072
    const int j = idx >> 10, k = idx & 1023;
    const float v = (j < 64) ? W1p[(size_t)k * 64 + j] : W2p[(size_t)k * 64 + (j - 64)];
    WB[(size_t)3072 * 1024 + idx] = f2b(v);
  } else {
    const size_t idx = ((size_t)(b - 4608) * 256 + t) << 2;
    const float4 v = *(const float4*)(x + idx);
    u16x4 o; o.x = f2b(v.x); o.y = f2b(v.y); o.z = f2b(v.z); o.w = f2b(v.w);
    *(u16x4*)(xb + idx) = o;
  }
}

// ---------------- 128x64 bf16 MFMA GEMM core (BK=64, global_load_lds, XOR swizzle) ----------------
static __device__ __forceinline__ void gemm_core_128x64(const u16* __restrict__ A, const u16* __restrict__ B,
                                                        int brow, int bcol, int K,
                                                        u16* ldsA, u16* ldsB, f32x4 acc[4][2]) {
  const int tid = threadIdx.x;
  const int wave = tid >> 6, lane = tid & 63;
  const int wr = wave >> 1, wc = wave & 1;
  const int g = lane >> 4, l15 = lane & 15;

  for (int k0 = 0; k0 < K; k0 += 64) {
#pragma unroll
    for (int li = 0; li < 4; ++li) {
      const int f = li * 256 + wave * 64 + lane;
      const int row = f >> 3;
      const int slot = f & 7;
      const int gcol = ((slot ^ (row & 7)) << 3);
      gload16(A + (size_t)(brow + row) * K + k0 + gcol, ldsA + (size_t)(li * 256 + wave * 64) * 8);
    }
#pragma unroll
    for (int li = 0; li < 2; ++li) {
      const int f = li * 256 + wave * 64 + lane;
      const int row = f >> 3;
      const int slot = f & 7;
      const int gcol = ((slot ^ (row & 7)) << 3);
      gload16(B + (size_t)(bcol + row) * K + k0 + gcol, ldsB + (size_t)(li * 256 + wave * 64) * 8);
    }
    __syncthreads();
    bf16x8 af[4][2], bfr[2][2];
#pragma unroll
    for (int kk = 0; kk < 2; ++kk) {
#pragma unroll
      for (int m = 0; m < 4; ++m) {
        const int rowA = wr * 64 + m * 16 + l15;
        const int chA = (kk * 4 + g) ^ (rowA & 7);
        af[m][kk] = *(const bf16x8*)(ldsA + (size_t)rowA * 64 + chA * 8);
      }
#pragma unroll
      for (int n = 0; n < 2; ++n) {
        const int rowB = wc * 32 + n * 16 + l15;
        const int chB = (kk * 4 + g) ^ (rowB & 7);
        bfr[n][kk] = *(const bf16x8*)(ldsB + (size_t)rowB * 64 + chB * 8);
      }
    }
#pragma unroll
    for (int m = 0; m < 4; ++m)
#pragma unroll
      for (int n = 0; n < 2; ++n)
#pragma unroll
        for (int kk = 0; kk < 2; ++kk)
          acc[m][n] = MFMA16(af[m][kk], bfr[n][kk], acc[m][n]);
    __syncthreads();
  }
}

// ---------------- GEMM1: x @ [Wqkv|W1p|W2p]  (M=2048, N=3200, K=1024) ----------------
// Q prescale = 0.125 * log2(e) so attention can use exp2 directly.
__global__ __launch_bounds__(256) void k_gemm_qkvp(const u16* __restrict__ xb, const u16* __restrict__ WB,
                                                   const float* __restrict__ bqkv,
                                                   u16* __restrict__ Qext, u16* __restrict__ Kext,
                                                   u16* __restrict__ Vt, float* __restrict__ P12) {
  __shared__ __align__(16) u16 ldsA[128 * 64];
  __shared__ __align__(16) u16 ldsB[64 * 64];
  const int bid = blockIdx.x;                      // 800 blocks
  const int bn = bid % 50, bm = bid / 50;
  f32x4 acc[4][2];
#pragma unroll
  for (int m = 0; m < 4; ++m)
#pragma unroll
    for (int n = 0; n < 2; ++n) acc[m][n] = (f32x4){0.f, 0.f, 0.f, 0.f};
  gemm_core_128x64(xb, WB, bm * 128, bn * 64, 1024, ldsA, ldsB, acc);

  const int tid = threadIdx.x;
  const int wave = tid >> 6, lane = tid & 63;
  const int wr = wave >> 1, wc = wave & 1;
  const int g = lane >> 4, l15 = lane & 15;
  const int tbase = bm * 128 + wr * 64 + g * 4;
  const int cbase = bn * 64 + wc * 32 + l15;
#pragma unroll
  for (int m = 0; m < 4; ++m) {
#pragma unroll
    for (int n = 0; n < 2; ++n) {
      const int c = cbase + n * 16;
#pragma unroll
      for (int r = 0; r < 4; ++r) {
        const int t = tbase + m * 16 + r;
        float v = acc[m][n][r];
        if (c < 3072) {
          v += bqkv[c];
          const int sub = c >> 10;
          const int rem = c & 1023;
          const int hh = rem >> 6, d = rem & 63;
          if (sub == 0)      Qext[((size_t)hh * 2048 + t) * 96 + d] = f2b(v * 0.18033688f);
          else if (sub == 1) Kext[((size_t)hh * 2048 + t) * 96 + d] = f2b(v);
          else               Vt[((size_t)hh * 64 + d) * 2048 + t] = f2b(v);
        } else {
          P12[(size_t)t * 128 + (c - 3072)] = v;
        }
      }
    }
  }
}

// ---------------- Plucker lines -> Qext/Kext cols 64..95 ----------------
__global__ __launch_bounds__(256) void k_lines(const float* __restrict__ P12, const float* __restrict__ pscale,
                                               u16* __restrict__ Qext, u16* __restrict__ Kext) {
  const int idx = blockIdx.x * 256 + threadIdx.x;  // 32768 = 2048*16
  const int t = idx >> 4, h = idx & 15;
  const float* p = P12 + (size_t)t * 128;
  const float a0 = p[h * 4 + 0], a1 = p[h * 4 + 1], a2 = p[h * 4 + 2], a3 = p[h * 4 + 3];
  const float b0 = p[64 + h * 4 + 0], b1 = p[64 + h * 4 + 1], b2 = p[64 + h * 4 + 2], b3 = p[64 + h * 4 + 3];
  float L0 = a0 * b1 - a1 * b0;
  float L1 = a0 * b2 - a2 * b0;
  float L2 = a0 * b3 - a3 * b0;
  float L3 = a1 * b2 - a2 * b1;
  float L4 = a1 * b3 - a3 * b1;
  float L5 = a2 * b3 - a3 * b2;
  const float nrm = sqrtf(L0 * L0 + L1 * L1 + L2 * L2 + L3 * L3 + L4 * L4 + L5 * L5);
  const float inv = 1.0f / fmaxf(nrm, 1e-12f);
  L0 *= inv; L1 *= inv; L2 *= inv; L3 *= inv; L4 *= inv; L5 *= inv;
  const float s = pscale[h] * 1.44269504f;  // fold log2(e) into q-side bias
  u16* q = Qext + ((size_t)h * 2048 + t) * 96 + 64;
  u16* k = Kext + ((size_t)h * 2048 + t) * 96 + 64;
  q[0] = f2b(L0 * s); q[1] = f2b(L1 * s); q[2] = f2b(L2 * s);
  q[3] = f2b(L3 * s); q[4] = f2b(L4 * s); q[5] = f2b(L5 * s);
  // Jlines = J6 @ L : [L5, -L4, L3, L2, -L1, L0]
  k[0] = f2b(L5); k[1] = f2b(-L4); k[2] = f2b(L3);
  k[3] = f2b(L2); k[4] = f2b(-L1); k[5] = f2b(L0);
#pragma unroll
  for (int c = 6; c < 32; ++c) { q[c] = 0; k[c] = 0; }
}

// ---------------- fused causal attention, swapped-operand (S^T), no-max exp2 softmax ----------------
// Round-2 skeleton (known-good 58.7us) with ONE change: running-max machinery removed.
// Logits bounded (|qk/8 + 0.1*bias| * log2e < ~12) -> exp2 without max-shift is safe in fp32,
// and bf16 P precision is shift-invariant. Row-sum l is a per-lane deferred partial,
// reduced by 2 shuffles in the epilogue only.
__global__ __launch_bounds__(256) void k_attn(const u16* __restrict__ Qext, const u16* __restrict__ Kext,
                                              const u16* __restrict__ Vt, u16* __restrict__ AO) {
  const int idx = blockIdx.x;                     // 512 blocks
  const int half = idx >> 8;
  const int qt_raw = (idx & 255) >> 4;
  const int qt = half ? (31 - qt_raw) : qt_raw;   // pair long+short tiles per CU
  const int h = idx & 15;
  const int wave = threadIdx.x >> 6, lane = threadIdx.x & 63;
  const int g = lane >> 4, l15 = lane & 15;
  const int q0 = qt * 64 + wave * 16;
  const int q_glob = q0 + l15;
  const u16* Qh = Qext + (size_t)h * 2048 * 96;
  const u16* Kh = Kext + (size_t)h * 2048 * 96;
  const u16* Vh = Vt + (size_t)h * 64 * 2048;

  bf16x8 aq[3];  // Q as B-fragment: col q=l15, contraction c = ks*32 + g*8 + e
#pragma unroll
  for (int ks = 0; ks < 3; ++ks)
    aq[ks] = *(const bf16x8*)(Qh + (size_t)q_glob * 96 + ks * 32 + g * 8);

  f32x4 accO[4];
#pragma unroll
  for (int n = 0; n < 4; ++n) accO[n] = (f32x4){0.f, 0.f, 0.f, 0.f};
  float lrun = 0.f;

  const int jt_max = (q0 + 15) >> 5;
  const u16* Kbase = Kh + (size_t)l15 * 96 + g * 8;

  bf16x8 kA0[3], kA1[3], kB0[3], kB1[3];
#pragma unroll
  for (int ks = 0; ks < 3; ++ks) {
    kA0[ks] = *(const bf16x8*)(Kbase + ks * 32);
    kA1[ks] = *(const bf16x8*)(Kbase + 16 * 96 + ks * 32);
  }

#define ATTN_STEP(KC0, KC1, KN0, KN1)                                             \
  {                                                                               \
    const int jb = jt * 32;                                                       \
    f32x4 S0 = (f32x4){0.f, 0.f, 0.f, 0.f}, S1 = (f32x4){0.f, 0.f, 0.f, 0.f};     \
    __builtin_amdgcn_s_setprio(1);                                                \
    _Pragma("unroll")                                                             \
    for (int ks = 0; ks < 3; ++ks) {                                              \
      S0 = MFMA16(KC0[ks], aq[ks], S0);                                           \
      S1 = MFMA16(KC1[ks], aq[ks], S1);                                           \
    }                                                                             \
    __builtin_amdgcn_s_setprio(0);                                                \
    const int jbn = (jt < jt_max) ? jb + 32 : jb;                                 \
    const u16* kp = Kbase + (size_t)jbn * 96;                                     \
    _Pragma("unroll")                                                             \
    for (int ks = 0; ks < 3; ++ks) {                                              \
      KN0[ks] = *(const bf16x8*)(kp + ks * 32);                                   \
      KN1[ks] = *(const bf16x8*)(kp + 16 * 96 + ks * 32);                         \
    }                                                                             \
    bf16x8 av[4];                                                                 \
    _Pragma("unroll")                                                             \
    for (int n = 0; n < 4; ++n)                                                   \
      av[n] = *(const bf16x8*)(Vh + (size_t)(n * 16 + l15) * 2048 + jb + g * 8);  \
    if (jb + 31 > q0) {                                                           \
      _Pragma("unroll")                                                           \
      for (int r = 0; r < 4; ++r) {                                               \
        if (jb + g * 4 + r > q_glob) S0[r] = -1e30f;                              \
        if (jb + 16 + g * 4 + r > q_glob) S1[r] = -1e30f;                         \
      }                                                                           \
    }                                                                             \
    _Pragma("unroll")                                                             \
    for (int r = 0; r < 4; ++r) {                                                 \
      S0[r] = exp2fast(S0[r]);                                                    \
      S1[r] = exp2fast(S1[r]);                                                    \
    }                                                                             \
    lrun += ((S0[0] + S0[1]) + (S0[2] + S0[3])) + ((S1[0] + S1[1]) + (S1[2] + S1[3])); \
    const u32 w0 = pack2(S0[0], S0[1]);                                           \
    const u32 w1 = pack2(S0[2], S0[3]);                                           \
    const u32 w2 = pack2(S1[0], S1[1]);                                           \
    const u32 w3 = pack2(S1[2], S1[3]);                                           \
    const int src0 = ((g & 1) << 5) + l15;                                        \
    const int src1 = src0 + 16;                                                   \
    const u32 a0 = (u32)__shfl((int)w0, src0);                                    \
    const u32 a1 = (u32)__shfl((int)w2, src0);                                    \
    const u32 b0 = (u32)__shfl((int)w1, src0);                                    \
    const u32 b1 = (u32)__shfl((int)w3, src0);                                    \
    const u32 c0 = (u32)__shfl((int)w0, src1);                                    \
    const u32 c1 = (u32)__shfl((int)w2, src1);                                    \
    const u32 d0 = (u32)__shfl((int)w1, src1);                                    \
    const u32 d1 = (u32)__shfl((int)w3, src1);                                    \
    union { u32 u[4]; bf16x8 bv; } pb;                                            \
    pb.u[0] = (g & 2) ? a1 : a0;                                                  \
    pb.u[1] = (g & 2) ? b1 : b0;                                                  \
    pb.u[2] = (g & 2) ? c1 : c0;                                                  \
    pb.u[3] = (g & 2) ? d1 : d0;                                                  \
    __builtin_amdgcn_s_setprio(1);                                                \
    _Pragma("unroll")                                                             \
    for (int n = 0; n < 4; ++n) accO[n] = MFMA16(av[n], pb.bv, accO[n]);          \
    __builtin_amdgcn_s_setprio(0);                                                \
  }

  int jt = 0;
  for (;;) {
    ATTN_STEP(kA0, kA1, kB0, kB1);
    if (++jt > jt_max) break;
    ATTN_STEP(kB0, kB1, kA0, kA1);
    if (++jt > jt_max) break;
  }
#undef ATTN_STEP

  // epilogue: reduce row-sum partials across the 4 g-groups, normalize, store
  lrun += __shfl_xor(lrun, 16);
  lrun += __shfl_xor(lrun, 32);
  const float inv = 1.0f / lrun;
  u32* dst = (u32*)(AO + (size_t)q_glob * 1024 + h * 64 + g * 4);
#pragma unroll
  for (int n = 0; n < 4; ++n) {
    const u32 lo = pack2(accO[n][0] * inv, accO[n][1] * inv);
    const u32 hi = pack2(accO[n][2] * inv, accO[n][3] * inv);
    dst[n * 8 + 0] = lo;   // +n*16 u16 = +n*8 u32
    dst[n * 8 + 1] = hi;
  }
}

// ---------------- GEMM out: AO @ WoutT + bout  (M=2048, N=1024, K=1024) ----------------
__global__ __launch_bounds__(256) void k_gemm_out(const u16* __restrict__ AO, const u16* __restrict__ WoT,
                                                  const float* __restrict__ bout, float* __restrict__ out) {
  __shared__ __align__(16) u16 ldsA[128 * 64];
  __shared__ __align__(16) u16 ldsB[64 * 64];
  const int bid = blockIdx.x;                     // 256 blocks
  const int bn = bid & 15, bm = bid >> 4;
  f32x4 acc[4][2];
#pragma unroll
  for (int m = 0; m < 4; ++m)
#pragma unroll
    for (int n = 0; n < 2; ++n) acc[m][n] = (f32x4){0.f, 0.f, 0.f, 0.f};
  gemm_core_128x64(AO, WoT, bm * 128, bn * 64, 1024, ldsA, ldsB, acc);

  const int tid = threadIdx.x;
  const int wave = tid >> 6, lane = tid & 63;
  const int wr = wave >> 1, wc = wave & 1;
  const int g = lane >> 4, l15 = lane & 15;
  const int tbase = bm * 128 + wr * 64 + g * 4;
  const int cbase = bn * 64 + wc * 32 + l15;
#pragma unroll
  for (int m = 0; m < 4; ++m)
#pragma unroll
    for (int n = 0; n < 2; ++n) {
      const int c = cbase + n * 16;
      const float bb = bout[c];
#pragma unroll
      for (int r = 0; r < 4; ++r) {
        const int t = tbase + m * 16 + r;
        out[(size_t)t * 1024 + c] = acc[m][n][r] + bb;
      }
    }
}

// ---------------- launch ----------------
extern "C" void kernel_launch(void* const* d_in, const int* in_sizes, int n_in,
                              void* d_out, int out_size, void* d_ws, size_t ws_size,
                              hipStream_t stream) {
  const float* x      = (const float*)d_in[0];
  const float* Wqkv   = (const float*)d_in[1];
  const float* bqkv   = (const float*)d_in[2];
  const float* W1p    = (const float*)d_in[3];
  const float* W2p    = (const float*)d_in[4];
  const float* pscale = (const float*)d_in[5];
  const float* Wout   = (const float*)d_in[6];
  const float* bout   = (const float*)d_in[7];
  float* out = (float*)d_out;

  char* ws = (char*)d_ws;
  u16*   WB    = (u16*)(ws + 0);          // [3200][1024] bf16
  u16*   WoT   = (u16*)(ws + 6553600);    // [1024][1024] bf16
  u16*   xb    = (u16*)(ws + 8650752);    // [2048][1024] bf16
  u16*   Qext  = (u16*)(ws + 12845056);   // [16][2048][96] bf16 (q*0.1803 | s*log2e*L | 0)
  u16*   Kext  = (u16*)(ws + 19136512);   // [16][2048][96] bf16 (k | J·L | 0)
  u16*   Vt    = (u16*)(ws + 25427968);   // [16][64][2048] bf16
  float* P12   = (float*)(ws + 29622272); // [2048][128] f32
  u16*   AO    = (u16*)(ws + 30670848);   // [2048][1024] bf16

  k_prep<<<6656, 256, 0, stream>>>(Wqkv, Wout, W1p, W2p, x, WB, WoT, xb);
  k_gemm_qkvp<<<800, 256, 0, stream>>>(xb, WB, bqkv, Qext, Kext, Vt, P12);
  k_lines<<<128, 256, 0, stream>>>(P12, pscale, Qext, Kext);
  k_attn<<<512, 256, 0, stream>>>(Qext, Kext, Vt, AO);
  k_gemm_out<<<256, 256, 0, stream>>>(AO, WoT, bout, out);
}